// Round 5
// baseline (3529.102 us; speedup 1.0000x reference)
//
#include <hip/hip_runtime.h>
#include <hip/hip_bf16.h>

// RepWalk on MI355X (gfx950). Inputs are fp32 (verified round 4); output fp32.
// Round 5: replace per-chain VALU LSTM (L2-BW bound on Whh re-reads, 57% of
// runtime) with batched MFMA recurrence:
//   - 32 blocks (16/dir), block j owns 19|18 h-dims = 80 gate-cols
//     (col layout interleaved: c = 4*d' + gate, so i,f,g,o sit in adjacent lanes)
//   - W slice (hi+lo bf16) preloaded into VGPRs once per launch (80 VGPR/lane)
//   - h exchanged as bf16 via global, per-step device-scope counter barrier
//   - xproj (bias folded, col-permuted) initializes MFMA accumulators
//   - c-state fp32 in owner-lane registers, persisted to ws across chunks
// Aspect LSTM reuses the same kernel (8 positions).

typedef unsigned short u16;
typedef __attribute__((ext_vector_type(8))) short short8;
typedef __attribute__((ext_vector_type(4))) float floatx4;

#define NEGV -1e9f

__device__ __forceinline__ float bf2f(u16 u) {
    union { unsigned int i; float f; } x; x.i = ((unsigned int)u) << 16; return x.f;
}
__device__ __forceinline__ u16 f2bf(float f) {
    unsigned int u = __float_as_uint(f);
    unsigned int r = (u + 0x7fff + ((u >> 16) & 1)) >> 16;
    return (u16)r;
}
__device__ __forceinline__ float sigm(float x) { return 1.f / (1.f + expf(-x)); }
__device__ __forceinline__ float sigmf_(float x) { return 1.f / (1.f + __expf(-x)); }
__device__ __forceinline__ float tanhf_(float x) {
    float e = __expf(2.f * x); return 1.f - 2.f / (e + 1.f);
}
__device__ __forceinline__ float rdf(const void* p, size_t i, int flag) {
    return flag ? ((const float*)p)[i] : bf2f(((const u16*)p)[i]);
}

// block-j partition of the 300 h-dims: 12 blocks x 19 + 4 blocks x 18
__device__ __forceinline__ int nd_of(int j) { return (j < 12) ? 19 : 18; }
__device__ __forceinline__ int dbase_of(int j) { return (j < 12) ? j * 19 : 228 + (j - 12) * 18; }

// ---------------- dtype detect (kept; inputs proven fp32 but cheap) ----------------
__global__ void k_detect(const void* __restrict__ emb, int* __restrict__ flag) {
    __shared__ int cnt;
    if (threadIdx.x == 0) cnt = 0;
    __syncthreads();
    u16 x = ((const u16*)emb)[4096 + threadIdx.x];
    int e = (x >> 7) & 0xFF;
    if (e >= 0x8A) atomicAdd(&cnt, 1);
    __syncthreads();
    if (threadIdx.x == 0) *flag = (cnt > 8) ? 1 : 0;
}

// ---------------- small prep ----------------
__global__ void k_prep_small(const int* __restrict__ text, const int* __restrict__ asp,
                             int* __restrict__ lens) {
    int tid = threadIdx.x;
    if (tid < 64) {
        int c = 0;
        for (int s = 0; s < 128; ++s) c += (text[tid * 128 + s] != 0);
        lens[tid] = c;
    } else if (tid < 128) {
        int b = tid - 64; int c = 0;
        for (int a = 0; a < 8; ++a) c += (asp[b * 8 + a] != 0);
        lens[64 + b] = c;
    }
}

// gather embeddings for positions [base, base+csteps) -> hi/lo bf16, K pad 320
__global__ void k_embed_pos(const void* __restrict__ emb, const int* __restrict__ ids,
                            int base, int csteps, int stride, const int* __restrict__ flag,
                            u16* __restrict__ dhi, u16* __restrict__ dlo) {
    int i = blockIdx.x * 256 + threadIdx.x;
    if (i >= 64 * csteps * 320) return;
    int f = *flag;
    int r = i / 320, k = i - r * 320;
    int b = r / csteps, j = r - b * csteps;
    int id = ids[b * stride + base + j];
    float val = (k < 300) ? rdf(emb, (size_t)id * 300 + k, f) : 0.f;
    u16 hi = f2bf(val);
    dhi[i] = hi;
    dlo[i] = f2bf(val - bf2f(hi));
}

// Wih [2,1200,300] -> permuted padded [2560,320] hi/lo.
// perm row R: dir=R/1280, j=(R%1280)/80, c=R%80, d'=c>>2, q=c&3,
// gatecol = q*300 + dbase(j)+d'  (zero rows when d' >= nd(j))
__global__ void k_pad_wih_perm(const void* __restrict__ W, const int* __restrict__ flag,
                               u16* __restrict__ dhi, u16* __restrict__ dlo) {
    int i = blockIdx.x * 256 + threadIdx.x;
    if (i >= 2560 * 320) return;
    int f = *flag;
    int R = i / 320, k = i - R * 320;
    int dir = R / 1280, rr = R - dir * 1280;
    int j = rr / 80, c = rr - j * 80;
    int dp = c >> 2, q = c & 3;
    float val = 0.f;
    if (dp < nd_of(j) && k < 300) {
        int gc = q * 300 + dbase_of(j) + dp;
        val = rdf(W, (size_t)dir * 360000 + (size_t)gc * 300 + k, f);
    }
    u16 hi = f2bf(val);
    dhi[i] = hi;
    dlo[i] = f2bf(val - bf2f(hi));
}

// Whh [2,1200,300] -> permuted [2][1280 permcols][328 kpad] hi/lo (B[n][k] = Whh[gc][k])
__global__ void k_whh_perm(const void* __restrict__ W, const int* __restrict__ flag,
                           u16* __restrict__ dhi, u16* __restrict__ dlo) {
    int i = blockIdx.x * 256 + threadIdx.x;
    if (i >= 2 * 1280 * 328) return;
    int f = *flag;
    int dir = i / (1280 * 328), r = i - dir * (1280 * 328);
    int col = r / 328, k = r - col * 328;
    int j = col / 80, c = col - j * 80;
    int dp = c >> 2, q = c & 3;
    float val = 0.f;
    if (dp < nd_of(j) && k < 300) {
        int gc = q * 300 + dbase_of(j) + dp;
        val = rdf(W, (size_t)dir * 360000 + (size_t)gc * 300 + k, f);
    }
    u16 hi = f2bf(val);
    dhi[i] = hi;
    dlo[i] = f2bf(val - bf2f(hi));
}

// bih+bhh -> permuted bias [2560]
__global__ void k_bias_perm(const void* bi, const void* bh, const int* __restrict__ flag,
                            float* __restrict__ dst) {
    int i = blockIdx.x * 256 + threadIdx.x;
    if (i >= 2560) return;
    int f = *flag;
    int dir = i / 1280, rr = i - dir * 1280;
    int j = rr / 80, c = rr - j * 80;
    int dp = c >> 2, q = c & 3;
    float val = 0.f;
    if (dp < nd_of(j)) {
        int gc = q * 300 + dbase_of(j) + dp;
        val = rdf(bi, dir * 1200 + gc, f) + rdf(bh, dir * 1200 + gc, f);
    }
    dst[i] = val;
}

// lin1_W [2,600,1200] -> padded [2,640,1216] hi/lo
__global__ void k_pad_lin1(const void* __restrict__ W, const int* __restrict__ flag,
                           u16* __restrict__ dhi, u16* __restrict__ dlo) {
    int i = blockIdx.x * 256 + threadIdx.x;
    if (i >= 2 * 640 * 1216) return;
    int f = *flag;
    int dir = i / (640 * 1216), r = i - dir * (640 * 1216);
    int n = r / 1216, k = r - n * 1216;
    float val = (n < 600 && k < 1200)
        ? rdf(W, (size_t)dir * 720000 + (size_t)n * 1200 + k, f) : 0.f;
    u16 hi = f2bf(val);
    dhi[i] = hi;
    dlo[i] = f2bf(val - bf2f(hi));
}

// small tensors -> fp32: smallf = pw(8192)|l2w(1200)|l2b(2)|fcw(1800)|fcb(3); bl[1280]
__global__ void k_small(const void* pw, const void* l2w, const void* l2b,
                        const void* fcw, const void* fcb, const void* lb,
                        const int* __restrict__ flag,
                        float* __restrict__ dst, float* __restrict__ bl) {
    int i = blockIdx.x * 256 + threadIdx.x;
    int f = *flag;
    if (i < 8192)            dst[i] = rdf(pw, i, f);
    else if (i < 9392)       dst[i] = rdf(l2w, i - 8192, f);
    else if (i < 9394)       dst[i] = rdf(l2b, i - 9392, f);
    else if (i < 11194)      dst[i] = rdf(fcw, i - 9394, f);
    else if (i < 11197)      dst[i] = rdf(fcb, i - 11194, f);
    if (i < 1280) {
        int dir = i / 640, c = i - dir * 640;
        bl[i] = (c < 600) ? rdf(lb, dir * 600 + c, f) : 0.f;
    }
}

// ---------------- MFMA GEMM: C = (Ahi+Alo)[M,K] @ (Bhi+Blo)[N,K]^T ----------------
__global__ __launch_bounds__(256) void gemm_bt(
    const u16* __restrict__ Ahi, const u16* __restrict__ Alo, int lda,
    const u16* __restrict__ Bhi, const u16* __restrict__ Blo, int ldb,
    const float* __restrict__ bias,
    float* __restrict__ C, int ldc, int nstore, int K, int mode,
    const float* __restrict__ tg, const float* __restrict__ pw, float* __restrict__ vio,
    int mrowoff)
{
    int tid = threadIdx.x;
    int wave = tid >> 6, lane = tid & 63;
    int l15 = lane & 15, quad = lane >> 4;
    int m0 = blockIdx.x * 64 + wave * 16;
    int n0 = blockIdx.y * 64;

    const u16* Ap  = Ahi + (size_t)(m0 + l15) * lda + quad * 8;
    const u16* Ap2 = Alo + (size_t)(m0 + l15) * lda + quad * 8;
    const u16* Bp  = Bhi + (size_t)(n0 + l15) * ldb + quad * 8;
    const u16* Bp2 = Blo + (size_t)(n0 + l15) * ldb + quad * 8;

    floatx4 acc0 = {0.f, 0.f, 0.f, 0.f};
    floatx4 acc1 = acc0, acc2 = acc0, acc3 = acc0;

    int nk = K >> 5;
    for (int kc = 0; kc < nk; ++kc) {
        int ko = kc * 32;
        short8 bh0 = *(const short8*)(Bp + ko);
        short8 bh1 = *(const short8*)(Bp + (size_t)16 * ldb + ko);
        short8 bh2 = *(const short8*)(Bp + (size_t)32 * ldb + ko);
        short8 bh3 = *(const short8*)(Bp + (size_t)48 * ldb + ko);
        short8 bl0 = *(const short8*)(Bp2 + ko);
        short8 bl1 = *(const short8*)(Bp2 + (size_t)16 * ldb + ko);
        short8 bl2 = *(const short8*)(Bp2 + (size_t)32 * ldb + ko);
        short8 bl3 = *(const short8*)(Bp2 + (size_t)48 * ldb + ko);
        short8 a  = *(const short8*)(Ap + ko);
        short8 al = *(const short8*)(Ap2 + ko);
        acc0 = __builtin_amdgcn_mfma_f32_16x16x32_bf16(a, bh0, acc0, 0, 0, 0);
        acc1 = __builtin_amdgcn_mfma_f32_16x16x32_bf16(a, bh1, acc1, 0, 0, 0);
        acc2 = __builtin_amdgcn_mfma_f32_16x16x32_bf16(a, bh2, acc2, 0, 0, 0);
        acc3 = __builtin_amdgcn_mfma_f32_16x16x32_bf16(a, bh3, acc3, 0, 0, 0);
        acc0 = __builtin_amdgcn_mfma_f32_16x16x32_bf16(a, bl0, acc0, 0, 0, 0);
        acc1 = __builtin_amdgcn_mfma_f32_16x16x32_bf16(a, bl1, acc1, 0, 0, 0);
        acc2 = __builtin_amdgcn_mfma_f32_16x16x32_bf16(a, bl2, acc2, 0, 0, 0);
        acc3 = __builtin_amdgcn_mfma_f32_16x16x32_bf16(a, bl3, acc3, 0, 0, 0);
        acc0 = __builtin_amdgcn_mfma_f32_16x16x32_bf16(al, bh0, acc0, 0, 0, 0);
        acc1 = __builtin_amdgcn_mfma_f32_16x16x32_bf16(al, bh1, acc1, 0, 0, 0);
        acc2 = __builtin_amdgcn_mfma_f32_16x16x32_bf16(al, bh2, acc2, 0, 0, 0);
        acc3 = __builtin_amdgcn_mfma_f32_16x16x32_bf16(al, bh3, acc3, 0, 0, 0);
    }

    #pragma unroll
    for (int c = 0; c < 4; ++c) {
        floatx4 acc = (c == 0) ? acc0 : (c == 1) ? acc1 : (c == 2) ? acc2 : acc3;
        int col = n0 + c * 16 + l15;
        if (col >= nstore) continue;
        float bb = bias[col];
        #pragma unroll
        for (int r = 0; r < 4; ++r) {
            int row = m0 + quad * 4 + r;
            float val = acc[r] + bb;
            if (mode == 1) {
                val = val > 0.f ? val : 0.01f * val;
                int rg = row + mrowoff;
                float t = tg[rg];
                size_t vi = (size_t)rg * 600 + col;
                float vv = vio[vi];
                vio[vi] = pw[rg] * ((1.f - t) * val + t * vv);
            } else {
                C[(size_t)row * ldc + col] = val;
            }
        }
    }
}

// ---------------- batched MFMA LSTM recurrence ----------------
// grid = 32 blocks (blockIdx = dir*16 + j), 320 threads = 5 waves (wave = Ntile).
// xfp/xbp: xproj chunks, row = b*rpb + (p - pbase), ldx cols (perm layout, bias folded).
// whh hi/lo: [2][1280][328]. hbf: [2 dir][2 parity][64][328] bf16. cst: [2][64][304] f32.
// ctr: per-(dir,p) counters. vout row stride 600, offset dir*300.
__global__ __launch_bounds__(320, 1) void k_lstm_mfma(
    const float* __restrict__ xfp, const float* __restrict__ xbp, int ldx, int rpb,
    const u16* __restrict__ whh_hi, const u16* __restrict__ whh_lo,
    const int* __restrict__ lens, float* __restrict__ vout, int T,
    u16* __restrict__ hbf, float* __restrict__ cst, int* __restrict__ ctr,
    int pbase_f, int pbase_b, int nsteps, int pmax, int init)
{
    __shared__ u16 Ah[64 * 328];
    int tid = threadIdx.x;
    int w = tid >> 6, lane = tid & 63;
    int l15 = lane & 15, quad = lane >> 4;
    int dir = blockIdx.x >> 4, j = blockIdx.x & 15;

    int nd = nd_of(j), dbase = dbase_of(j);
    int c = 16 * w + l15;
    int myd = c >> 2, q = c & 3;
    bool owner = (q == 0) && (myd < nd);
    int gdim = dbase + myd;

    // preload W fragments (stationary across all steps)
    short8 wfh[10], wfl[10];
    {
        size_t base = ((size_t)(dir * 1280 + j * 80 + c)) * 328 + quad * 8;
        #pragma unroll
        for (int ks = 0; ks < 10; ++ks) {
            wfh[ks] = *(const short8*)(whh_hi + base + (size_t)ks * 32);
            wfl[ks] = *(const short8*)(whh_lo + base + (size_t)ks * 32);
        }
    }
    int lenv[16];
    float creg[16];
    #pragma unroll
    for (int m = 0; m < 4; ++m)
        #pragma unroll
        for (int r = 0; r < 4; ++r) {
            int b = 16 * m + quad * 4 + r;
            lenv[m * 4 + r] = lens[b];
            creg[m * 4 + r] = 0.f;
        }
    if (!init && owner) {
        #pragma unroll
        for (int m = 0; m < 4; ++m)
            #pragma unroll
            for (int r = 0; r < 4; ++r) {
                int b = 16 * m + quad * 4 + r;
                creg[m * 4 + r] = cst[(size_t)(dir * 64 + b) * 304 + gdim];
            }
    }

    for (int s = 0; s < nsteps; ++s) {
        int p = dir ? (pbase_b + nsteps - 1 - s) : (pbase_f + s);
        int cur = dir ? ((pmax - p) & 1) : (p & 1);
        int nxt = cur ^ 1;
        const u16* hsrc = hbf + (size_t)(dir * 2 + cur) * 64 * 328;
        u16* hdst = hbf + (size_t)(dir * 2 + nxt) * 64 * 328;

        __syncthreads();                              // protect Ah from prior readers
        for (int i = tid; i < 2624; i += 320)
            ((uint4*)Ah)[i] = ((const uint4*)hsrc)[i];
        __syncthreads();

        int rel = dir ? (p - pbase_b) : (p - pbase_f);
        const float* xsrc = (dir ? xbp : xfp) + (size_t)rel * ldx;
        floatx4 acc[4];
        #pragma unroll
        for (int m = 0; m < 4; ++m) {
            #pragma unroll
            for (int r = 0; r < 4; ++r) {
                int b = 16 * m + quad * 4 + r;
                acc[m][r] = xsrc[(size_t)b * rpb * ldx + j * 80 + c];
            }
        }
        #pragma unroll
        for (int ks = 0; ks < 10; ++ks) {
            #pragma unroll
            for (int m = 0; m < 4; ++m) {
                short8 a = *(const short8*)(Ah + (16 * m + l15) * 328 + ks * 32 + quad * 8);
                acc[m] = __builtin_amdgcn_mfma_f32_16x16x32_bf16(a, wfh[ks], acc[m], 0, 0, 0);
                acc[m] = __builtin_amdgcn_mfma_f32_16x16x32_bf16(a, wfl[ks], acc[m], 0, 0, 0);
            }
        }
        // gates: apply nonlinearity per-lane (q2 -> tanh, else sigmoid), then
        // gather i,f,g,o from the 4-lane quad via shfl_xor; q0 lanes own the dim.
        #pragma unroll
        for (int m = 0; m < 4; ++m) {
            #pragma unroll
            for (int r = 0; r < 4; ++r) {
                int idx = m * 4 + r;
                float x0 = acc[m][r];
                float act = (q == 2) ? tanhf_(x0) : sigmf_(x0);
                float gi = act;
                float gf = __shfl_xor(act, 1, 64);
                float gg = __shfl_xor(act, 2, 64);
                float go = __shfl_xor(act, 3, 64);
                float cn = gf * creg[idx] + gi * gg;
                float hn = go * tanhf_(cn);
                int b = 16 * m + quad * 4 + r;
                bool valid = owner && (p < lenv[idx]);
                if (valid) {
                    creg[idx] = cn;
                    vout[((size_t)b * T + p) * 600 + dir * 300 + gdim] = hn;
                }
                if (owner) {
                    u16 hold = Ah[b * 328 + gdim];
                    hdst[b * 328 + gdim] = valid ? f2bf(hn) : hold;
                }
            }
        }
        __threadfence();
        __syncthreads();
        if (tid == 0) {
            int* cp = &ctr[dir * 128 + p];
            __hip_atomic_fetch_add(cp, 1, __ATOMIC_ACQ_REL, __HIP_MEMORY_SCOPE_AGENT);
            while (__hip_atomic_load(cp, __ATOMIC_ACQUIRE, __HIP_MEMORY_SCOPE_AGENT) < 16)
                __builtin_amdgcn_s_sleep(2);
        }
        __syncthreads();
    }
    if (owner) {
        #pragma unroll
        for (int m = 0; m < 4; ++m)
            #pragma unroll
            for (int r = 0; r < 4; ++r) {
                int b = 16 * m + quad * 4 + r;
                cst[(size_t)(dir * 64 + b) * 304 + gdim] = creg[m * 4 + r];
            }
    }
}

// ---------------- attention ----------------
__global__ __launch_bounds__(64) void k_scores(
    const float* __restrict__ v, const float* __restrict__ e,
    const int* __restrict__ text, const int* __restrict__ asp,
    const float* __restrict__ l2w, const float* __restrict__ l2b, int iter,
    float* __restrict__ a_sm, float* __restrict__ tg)
{
    int row = blockIdx.x, b = row >> 7, lane = threadIdx.x;
    float acc[9];
    #pragma unroll
    for (int j = 0; j < 9; ++j) acc[j] = 0.f;
    const float* vrow = v + (size_t)row * 600;
    const float* eb = e + (size_t)b * 4800;
    const float* w2 = l2w + iter * 600;
    for (int d = lane; d < 600; d += 64) {
        float vv = vrow[d];
        #pragma unroll
        for (int a = 0; a < 8; ++a) acc[a] += vv * eb[a * 600 + d];
        acc[8] += vv * w2[d];
    }
    #pragma unroll
    for (int off = 32; off >= 1; off >>= 1) {
        #pragma unroll
        for (int j = 0; j < 9; ++j) acc[j] += __shfl_down(acc[j], off, 64);
    }
    if (lane == 0) {
        tg[row] = sigm(acc[8] + l2b[iter]);
        bool sm = (text[row] != 0);
        float sc[8]; float mx = -INFINITY;
        #pragma unroll
        for (int a = 0; a < 8; ++a) {
            sc[a] = (sm && asp[b * 8 + a] != 0) ? acc[a] : NEGV;
            mx = fmaxf(mx, sc[a]);
        }
        float den = 0.f;
        #pragma unroll
        for (int a = 0; a < 8; ++a) { sc[a] = expf(sc[a] - mx); den += sc[a]; }
        float inv = 1.f / den;
        #pragma unroll
        for (int a = 0; a < 8; ++a) a_sm[(size_t)row * 8 + a] = sc[a] * inv;
    }
}

__global__ void k_midcat(const float* __restrict__ a_sm, const float* __restrict__ e,
                         const float* __restrict__ v, int rowoff,
                         u16* __restrict__ cat_hi, u16* __restrict__ cat_lo)
{
    int d = blockIdx.x * 256 + threadIdx.x;
    int rl = blockIdx.y;
    if (d >= 1216) return;
    int row = rowoff + rl;
    int b = row >> 7;
    float val;
    if (d < 600) {
        const float* as = a_sm + (size_t)row * 8;
        const float* eb = e + (size_t)b * 4800 + d;
        float m = 0.f;
        #pragma unroll
        for (int a = 0; a < 8; ++a) m += as[a] * eb[a * 600];
        val = m;
    } else if (d < 1200) {
        val = v[(size_t)row * 600 + (d - 600)];
    } else {
        val = 0.f;
    }
    u16 hi = f2bf(val);
    cat_hi[(size_t)rl * 1216 + d] = hi;
    cat_lo[(size_t)rl * 1216 + d] = f2bf(val - bf2f(hi));
}

// ---------------- final ----------------
__global__ void k_query(const float* __restrict__ e, const int* __restrict__ asp,
                        float* __restrict__ q) {
    int i = blockIdx.x * 256 + threadIdx.x;
    if (i >= 64 * 600) return;
    int b = i / 600, d = i - b * 600;
    float m = NEGV;
    for (int a = 0; a < 8; ++a)
        if (asp[b * 8 + a] != 0) m = fmaxf(m, e[(size_t)b * 4800 + a * 600 + d]);
    q[i] = m;
}

__global__ __launch_bounds__(128) void k_final(
    const float* __restrict__ v, const float* __restrict__ q,
    const int* __restrict__ text, const float* __restrict__ fcW,
    const float* __restrict__ fcb, const int* __restrict__ flag, void* __restrict__ outv)
{
    __shared__ float red[128];
    __shared__ float al[128];
    __shared__ float zz[600];
    int b = blockIdx.x, s = threadIdx.x;
    const float* vrow = v + (size_t)(b * 128 + s) * 600;
    const float* qb = q + (size_t)b * 600;
    float sc = 0.f;
    for (int d = 0; d < 600; ++d) sc += vrow[d] * qb[d];
    if (text[b * 128 + s] == 0) sc = NEGV;
    red[s] = sc; __syncthreads();
    for (int off = 64; off >= 1; off >>= 1) {
        if (s < off) red[s] = fmaxf(red[s], red[s + off]);
        __syncthreads();
    }
    float mx = red[0]; __syncthreads();
    float ex = expf(sc - mx);
    red[s] = ex; __syncthreads();
    for (int off = 64; off >= 1; off >>= 1) {
        if (s < off) red[s] += red[s + off];
        __syncthreads();
    }
    float alpha = ex / red[0];
    al[s] = alpha; __syncthreads();
    for (int d = s; d < 600; d += 128) {
        float z = 0.f;
        for (int s2 = 0; s2 < 128; ++s2) z += al[s2] * v[(size_t)(b * 128 + s2) * 600 + d];
        zz[d] = z;
    }
    __syncthreads();
    if (s < 3) {
        float o = 0.f;
        for (int d = 0; d < 600; ++d) o += zz[d] * fcW[s * 600 + d];
        o += fcb[s];
        if (*flag) ((float*)outv)[b * 3 + s] = o;
        else       ((u16*)outv)[b * 3 + s] = f2bf(o);
    }
}

// ---------------- host launch ----------------
extern "C" void kernel_launch(void* const* d_in, const int* in_sizes, int n_in,
                              void* d_out, int out_size, void* d_ws, size_t ws_size,
                              hipStream_t stream) {
    const int*  text   = (const int*)d_in[0];
    const int*  asp    = (const int*)d_in[1];
    const void* pw     = d_in[2];
    const void* emb    = d_in[3];
    const void* l1_Wih = d_in[4];
    const void* l1_Whh = d_in[5];
    const void* l1_bih = d_in[6];
    const void* l1_bhh = d_in[7];
    const void* l2_Wih = d_in[8];
    const void* l2_Whh = d_in[9];
    const void* l2_bih = d_in[10];
    const void* l2_bhh = d_in[11];
    const void* lin1_W = d_in[12];
    const void* lin1_b = d_in[13];
    const void* lin2_W = d_in[14];
    const void* lin2_b = d_in[15];
    const void* fcW    = d_in[16];
    const void* fcb    = d_in[17];
    (void)ws_size; (void)n_in; (void)in_sizes; (void)out_size;

    char* w = (char*)d_ws;
    size_t off = 0;
    auto alloc = [&](size_t bytes) -> void* {
        void* p = w + off;
        off += (bytes + 255) & ~(size_t)255;
        return p;
    };
    // ---- persistent (~22 MB) ----
    int*   flag     = (int*)  alloc(4);
    int*   lens     = (int*)  alloc(128ull * 4);
    float* bias_l1  = (float*)alloc(1280ull * 4);
    float* smallf   = (float*)alloc(11197ull * 4);
    float* bperm_t  = (float*)alloc(2560ull * 4);
    float* bperm_a  = (float*)alloc(2560ull * 4);
    float* tg       = (float*)alloc(8192ull * 4);
    float* a_sm     = (float*)alloc(8192ull * 8 * 4);
    float* query    = (float*)alloc(64ull * 600 * 4);
    u16*   hbf_t    = (u16*)  alloc(4ull * 64 * 328 * 2);
    u16*   hbf_a    = (u16*)  alloc(4ull * 64 * 328 * 2);
    float* cst_t    = (float*)alloc(2ull * 64 * 304 * 4);
    float* cst_a    = (float*)alloc(2ull * 64 * 304 * 4);
    int*   ctr      = (int*)  alloc(512ull * 4);
    float* e        = (float*)alloc(512ull * 600 * 4);
    float* v        = (float*)alloc(8192ull * 600 * 4);
    float* pw_f     = smallf;
    float* l2w_f    = smallf + 8192;
    float* l2b_f    = smallf + 9392;
    float* fcW_f    = smallf + 9394;
    float* fcb_f    = smallf + 11194;
    // ---- phase region (union, ~28 MB) ----
    size_t phase_off = off;
    u16*   wfcf_hi  = (u16*)  alloc(1024ull * 320 * 2);
    u16*   wfcf_lo  = (u16*)  alloc(1024ull * 320 * 2);
    u16*   wfcb_hi  = (u16*)  alloc(1024ull * 320 * 2);
    u16*   wfcb_lo  = (u16*)  alloc(1024ull * 320 * 2);
    u16*   af_hi    = (u16*)  alloc(512ull * 320 * 2);
    u16*   af_lo    = (u16*)  alloc(512ull * 320 * 2);
    u16*   wipt_hi  = (u16*)  alloc(2560ull * 320 * 2);
    u16*   wipt_lo  = (u16*)  alloc(2560ull * 320 * 2);
    u16*   wipa_hi  = (u16*)  alloc(2560ull * 320 * 2);
    u16*   wipa_lo  = (u16*)  alloc(2560ull * 320 * 2);
    u16*   whpt_hi  = (u16*)  alloc(2ull * 1280 * 328 * 2);
    u16*   whpt_lo  = (u16*)  alloc(2ull * 1280 * 328 * 2);
    u16*   whpa_hi  = (u16*)  alloc(2ull * 1280 * 328 * 2);
    u16*   whpa_lo  = (u16*)  alloc(2ull * 1280 * 328 * 2);
    float* xf       = (float*)alloc(1024ull * 1280 * 4);   // also aliases xa [512][2560]
    float* xb       = (float*)alloc(1024ull * 1280 * 4);
    float* xa       = xf;
    // phase B aliases phase A
    off = phase_off;
    u16*   l1w_hi   = (u16*)  alloc(2ull * 640 * 1216 * 2);
    u16*   l1w_lo   = (u16*)  alloc(2ull * 640 * 1216 * 2);
    u16*   cat_hi   = (u16*)  alloc(2048ull * 1216 * 2);
    u16*   cat_lo   = (u16*)  alloc(2048ull * 1216 * 2);

    hipMemsetAsync(v, 0, 8192ull * 600 * 4, stream);
    hipMemsetAsync(e, 0, 512ull * 600 * 4, stream);
    hipMemsetAsync(hbf_t, 0, 4ull * 64 * 328 * 2, stream);
    hipMemsetAsync(hbf_a, 0, 4ull * 64 * 328 * 2, stream);
    hipMemsetAsync(ctr, 0, 512ull * 4, stream);

    // ---- prep ----
    k_detect<<<1, 256, 0, stream>>>(emb, flag);
    k_prep_small<<<1, 128, 0, stream>>>(text, asp, lens);
    k_pad_wih_perm<<<(2560 * 320 + 255) / 256, 256, 0, stream>>>(l1_Wih, flag, wipt_hi, wipt_lo);
    k_pad_wih_perm<<<(2560 * 320 + 255) / 256, 256, 0, stream>>>(l2_Wih, flag, wipa_hi, wipa_lo);
    k_whh_perm<<<(2 * 1280 * 328 + 255) / 256, 256, 0, stream>>>(l1_Whh, flag, whpt_hi, whpt_lo);
    k_whh_perm<<<(2 * 1280 * 328 + 255) / 256, 256, 0, stream>>>(l2_Whh, flag, whpa_hi, whpa_lo);
    k_bias_perm<<<10, 256, 0, stream>>>(l1_bih, l1_bhh, flag, bperm_t);
    k_bias_perm<<<10, 256, 0, stream>>>(l2_bih, l2_bhh, flag, bperm_a);
    k_small<<<49, 256, 0, stream>>>(pw, lin2_W, lin2_b, fcW, fcb, lin1_b, flag,
                                    smallf, bias_l1);

    // ---- aspect path (xa aliases xf; done before text chunks) ----
    k_embed_pos<<<(512 * 320 + 255) / 256, 256, 0, stream>>>(emb, asp, 0, 8, 8, flag,
                                                             af_hi, af_lo);
    gemm_bt<<<dim3(8, 40), 256, 0, stream>>>(af_hi, af_lo, 320, wipa_hi, wipa_lo, 320,
        bperm_a, xa, 2560, 2560, 320, 0, nullptr, nullptr, nullptr, 0);
    k_lstm_mfma<<<32, 320, 0, stream>>>(xa, xa + 1280, 2560, 8,
        whpa_hi, whpa_lo, lens + 64, e, 8, hbf_a, cst_a, ctr + 256, 0, 0, 8, 7, 1);

    // ---- text path: 8 chunks of 16 positions ----
    for (int kk = 0; kk < 8; ++kk) {
        int bf = 16 * kk;
        int bb = 112 - 16 * kk;
        k_embed_pos<<<(1024 * 320 + 255) / 256, 256, 0, stream>>>(emb, text, bf, 16, 128,
                                                                  flag, wfcf_hi, wfcf_lo);
        k_embed_pos<<<(1024 * 320 + 255) / 256, 256, 0, stream>>>(emb, text, bb, 16, 128,
                                                                  flag, wfcb_hi, wfcb_lo);
        gemm_bt<<<dim3(16, 20), 256, 0, stream>>>(wfcf_hi, wfcf_lo, 320,
            wipt_hi, wipt_lo, 320, bperm_t, xf, 1280, 1280, 320, 0,
            nullptr, nullptr, nullptr, 0);
        gemm_bt<<<dim3(16, 20), 256, 0, stream>>>(wfcb_hi, wfcb_lo, 320,
            wipt_hi + 1280ull * 320, wipt_lo + 1280ull * 320, 320, bperm_t + 1280,
            xb, 1280, 1280, 320, 0, nullptr, nullptr, nullptr, 0);
        k_lstm_mfma<<<32, 320, 0, stream>>>(xf, xb, 1280, 16,
            whpt_hi, whpt_lo, lens, v, 128, hbf_t, cst_t, ctr, bf, bb, 16, 127, kk == 0);
    }

    // ---- phase B prep ----
    k_pad_lin1<<<(2 * 640 * 1216 + 255) / 256, 256, 0, stream>>>(lin1_W, flag,
                                                                 l1w_hi, l1w_lo);

    // ---- two attention iterations ----
    for (int iter = 0; iter < 2; ++iter) {
        k_scores<<<8192, 64, 0, stream>>>(v, e, text, asp, l2w_f, l2b_f, iter, a_sm, tg);
        for (int c = 0; c < 4; ++c) {
            int rowoff = c * 2048;
            k_midcat<<<dim3(5, 2048), 256, 0, stream>>>(a_sm, e, v, rowoff, cat_hi, cat_lo);
            gemm_bt<<<dim3(32, 10), 256, 0, stream>>>(cat_hi, cat_lo, 1216,
                l1w_hi + (size_t)iter * 640 * 1216, l1w_lo + (size_t)iter * 640 * 1216,
                1216, bias_l1 + iter * 640,
                nullptr, 0, 600, 1216, 1, tg, pw_f, v, rowoff);
        }
    }

    // ---- final ----
    k_query<<<150, 256, 0, stream>>>(e, asp, query);
    k_final<<<64, 128, 0, stream>>>(v, query, text, fcW_f, fcb_f, flag, d_out);
}